// Round 1
// baseline (273.991 us; speedup 1.0000x reference)
//
#include <hip/hip_runtime.h>

#define BB   2
#define NNN  2048
#define DIN  256
#define HH   8
#define DHD  32
#define NW   (NNN/64)   // 32 mask words per row

typedef __attribute__((ext_vector_type(8))) short short8;
typedef __attribute__((ext_vector_type(4))) float f32x4;

__device__ __forceinline__ unsigned short f2bf(float f) {
  unsigned int u = __float_as_uint(f);
  u += 0x7fffu + ((u >> 16) & 1u);   // round-to-nearest-even
  return (unsigned short)(u >> 16);
}

// ---------------- K0: adjacency -> 64-bit masks ----------------
__global__ __launch_bounds__(256) void build_mask(const float* __restrict__ adj,
                                                  unsigned long long* __restrict__ Mk) {
  size_t i = (size_t)blockIdx.x * 256 + threadIdx.x;   // over B*N*N
  float v = adj[i];
  unsigned long long bm = __ballot(v != 0.0f);
  if ((threadIdx.x & 63) == 0) Mk[i >> 6] = bm;
}

// ---------------- K1: QKV projection (fp32 acc -> bf16) ----------------
// 16 rows per block; Q pre-scaled by (1/sqrt(DH))*log2(e)
__global__ __launch_bounds__(256) void qkv_proj(
    const float* __restrict__ x, const float* __restrict__ Wq,
    const float* __restrict__ Wk, const float* __restrict__ Wv,
    unsigned short* __restrict__ Qb, unsigned short* __restrict__ Kb,
    unsigned short* __restrict__ Vb) {
  __shared__ float xt[16][DIN];
  const int t = threadIdx.x;
  const int row0 = blockIdx.x * 16;
  for (int r = 0; r < 16; ++r) xt[r][t] = x[(size_t)(row0 + r) * DIN + t];
  __syncthreads();

  float aq[16], ak[16], av[16];
  #pragma unroll
  for (int r = 0; r < 16; ++r) { aq[r] = 0.f; ak[r] = 0.f; av[r] = 0.f; }

  const float4* wq = (const float4*)(Wq + (size_t)t * DIN);
  const float4* wk = (const float4*)(Wk + (size_t)t * DIN);
  const float4* wv = (const float4*)(Wv + (size_t)t * DIN);

  for (int k = 0; k < DIN / 4; ++k) {
    float4 q4 = wq[k], k4 = wk[k], v4 = wv[k];
    #pragma unroll
    for (int r = 0; r < 16; ++r) {
      float4 xx = *(const float4*)&xt[r][k * 4];
      aq[r] += xx.x*q4.x + xx.y*q4.y + xx.z*q4.z + xx.w*q4.w;
      ak[r] += xx.x*k4.x + xx.y*k4.y + xx.z*k4.z + xx.w*k4.w;
      av[r] += xx.x*v4.x + xx.y*v4.y + xx.z*v4.z + xx.w*v4.w;
    }
  }

  const float QSCALE = 0.17677669529663687f * 1.4426950408889634f;
  const int h = t >> 5, dh = t & 31;
  #pragma unroll
  for (int r = 0; r < 16; ++r) {
    int row = row0 + r;
    int b = row >> 11, nn = row & (NNN - 1);
    size_t off = ((size_t)(b * HH + h) * NNN + nn) * DHD + dh;
    Qb[off] = f2bf(aq[r] * QSCALE);
    Kb[off] = f2bf(ak[r]);
    Vb[off] = f2bf(av[r]);
  }
}

// ---------------- K1b: V -> V^T  (Vt[bh][dh][n]) ----------------
__global__ __launch_bounds__(256) void transpose_v(const unsigned short* __restrict__ Vb,
                                                   unsigned short* __restrict__ Vt) {
  __shared__ __align__(16) unsigned short tile[64][48];
  const int t = threadIdx.x;
  const int nb = blockIdx.x * 64;
  const int bh = blockIdx.y;
  {
    int nr = t >> 2, c0 = (t & 3) * 8;
    short8 v = *(const short8*)(Vb + ((size_t)bh * NNN + nb + nr) * DHD + c0);
    *(short8*)&tile[nr][c0] = v;
  }
  __syncthreads();
  {
    int dh = t >> 3, n0 = (t & 7) * 8;
    unsigned short tmp[8];
    #pragma unroll
    for (int j = 0; j < 8; ++j) tmp[j] = tile[n0 + j][dh];
    *(short8*)(Vt + ((size_t)bh * DHD + dh) * NNN + nb + n0) = *(const short8*)tmp;
  }
}

// ---------------- K2: fused masked flash attention ----------------
// block = 4 waves; wave w handles q rows [qt*64 + w*16, +16); loops over 32 key tiles of 64
__global__ __launch_bounds__(256) void attn(
    const unsigned short* __restrict__ Qb, const unsigned short* __restrict__ Kb,
    const unsigned short* __restrict__ Vt, const unsigned long long* __restrict__ Mk,
    float* __restrict__ AO) {
  __shared__ __align__(16) unsigned short P[2][4][16][88];  // double-buffered, stride 88 (conflict-free b128)
  const int l = threadIdx.x & 63;
  const int w = threadIdx.x >> 6;
  const int col = l & 15, quad = l >> 4;
  const int qt = blockIdx.x, h = blockIdx.y, b = blockIdx.z;
  const int bh = b * HH + h;
  const int qrow0 = qt * 64 + w * 16;

  const short8 aq = *(const short8*)(Qb + ((size_t)bh * NNN + qrow0 + col) * DHD + quad * 8);

  f32x4 acc0 = {0.f, 0.f, 0.f, 0.f}, acc1 = {0.f, 0.f, 0.f, 0.f};
  float mi[4], li[4];
  #pragma unroll
  for (int r = 0; r < 4; ++r) { mi[r] = -1e30f; li[r] = 0.f; }

  const size_t mbase = ((size_t)b * NNN + qrow0 + quad * 4) * NW;

  for (int kt = 0; kt < NW; ++kt) {
    const int kbase = kt * 64;
    const f32x4 z = {0.f, 0.f, 0.f, 0.f};
    f32x4 s[4];
    #pragma unroll
    for (int c = 0; c < 4; ++c) {
      short8 bk = *(const short8*)(Kb + ((size_t)bh * NNN + kbase + c * 16 + col) * DHD + quad * 8);
      s[c] = __builtin_amdgcn_mfma_f32_16x16x32_bf16(aq, bk, z, 0, 0, 0);
    }
    unsigned long long mw[4];
    #pragma unroll
    for (int r = 0; r < 4; ++r) mw[r] = Mk[mbase + (size_t)r * NW + kt];

    float p[4][4], alpha[4];
    #pragma unroll
    for (int r = 0; r < 4; ++r) {
      float tv[4];
      #pragma unroll
      for (int c = 0; c < 4; ++c) {
        bool ok = (mw[r] >> (c * 16 + col)) & 1ull;
        tv[c] = ok ? s[c][r] : -1e30f;     // scores already scaled by 1/sqrt(dh)*log2e via Q
      }
      float vm = fmaxf(fmaxf(tv[0], tv[1]), fmaxf(tv[2], tv[3]));
      #pragma unroll
      for (int off = 1; off < 16; off <<= 1) vm = fmaxf(vm, __shfl_xor(vm, off, 64));
      float mnew = fmaxf(mi[r], vm);
      alpha[r] = exp2f(mi[r] - mnew);
      float rs = 0.f;
      #pragma unroll
      for (int c = 0; c < 4; ++c) {
        bool ok = (mw[r] >> (c * 16 + col)) & 1ull;
        float pv = ok ? exp2f(tv[c] - mnew) : 0.f;   // guard: all-masked tile must give 0
        p[r][c] = pv;
        rs += pv;
      }
      #pragma unroll
      for (int off = 1; off < 16; off <<= 1) rs += __shfl_xor(rs, off, 64);
      li[r] = li[r] * alpha[r] + rs;
      mi[r] = mnew;
    }
    #pragma unroll
    for (int r = 0; r < 4; ++r) { acc0[r] *= alpha[r]; acc1[r] *= alpha[r]; }

    unsigned short* Pw = &P[kt & 1][w][0][0];
    #pragma unroll
    for (int r = 0; r < 4; ++r)
      #pragma unroll
      for (int c = 0; c < 4; ++c)
        Pw[(quad * 4 + r) * 88 + c * 16 + col] = f2bf(p[r][c]);

    __syncthreads();  // orders P writes->reads (lanes are distinct threads) and buffer reuse

    #pragma unroll
    for (int kk = 0; kk < 2; ++kk) {
      short8 pf = *(const short8*)(Pw + col * 88 + kk * 32 + quad * 8);
      short8 v0 = *(const short8*)(Vt + ((size_t)bh * DHD + col) * NNN + kbase + kk * 32 + quad * 8);
      short8 v1 = *(const short8*)(Vt + ((size_t)bh * DHD + 16 + col) * NNN + kbase + kk * 32 + quad * 8);
      acc0 = __builtin_amdgcn_mfma_f32_16x16x32_bf16(pf, v0, acc0, 0, 0, 0);
      acc1 = __builtin_amdgcn_mfma_f32_16x16x32_bf16(pf, v1, acc1, 0, 0, 0);
    }
  }

  #pragma unroll
  for (int r = 0; r < 4; ++r) {
    float inv = 1.0f / li[r];
    size_t o = ((size_t)b * NNN + qrow0 + quad * 4 + r) * (HH * DHD) + h * DHD;
    AO[o + col]      = acc0[r] * inv;
    AO[o + 16 + col] = acc1[r] * inv;
  }
}

// ---------------- K3: output projection + bias (fp32) ----------------
__global__ __launch_bounds__(256) void out_proj(const float* __restrict__ AO,
                                                const float* __restrict__ Wo,
                                                const float* __restrict__ bo,
                                                float* __restrict__ out) {
  __shared__ float xt[16][DIN];
  const int t = threadIdx.x;
  const int row0 = blockIdx.x * 16;
  for (int r = 0; r < 16; ++r) xt[r][t] = AO[(size_t)(row0 + r) * DIN + t];
  __syncthreads();

  float acc[16];
  #pragma unroll
  for (int r = 0; r < 16; ++r) acc[r] = 0.f;
  const float4* wo = (const float4*)(Wo + (size_t)t * DIN);
  for (int k = 0; k < DIN / 4; ++k) {
    float4 w4 = wo[k];
    #pragma unroll
    for (int r = 0; r < 16; ++r) {
      float4 xx = *(const float4*)&xt[r][k * 4];
      acc[r] += xx.x*w4.x + xx.y*w4.y + xx.z*w4.z + xx.w*w4.w;
    }
  }
  float bias = bo[t];
  #pragma unroll
  for (int r = 0; r < 16; ++r) out[(size_t)(row0 + r) * DIN + t] = acc[r] + bias;
}

extern "C" void kernel_launch(void* const* d_in, const int* in_sizes, int n_in,
                              void* d_out, int out_size, void* d_ws, size_t ws_size,
                              hipStream_t stream) {
  const float* x   = (const float*)d_in[0];
  const float* adj = (const float*)d_in[1];
  const float* Wq  = (const float*)d_in[2];
  const float* Wk  = (const float*)d_in[3];
  const float* Wv  = (const float*)d_in[4];
  const float* Wo  = (const float*)d_in[5];
  const float* bo  = (const float*)d_in[6];
  float* out = (float*)d_out;

  char* ws = (char*)d_ws;
  unsigned short* Qb = (unsigned short*)(ws);                      // 2 MB
  unsigned short* Kb = (unsigned short*)(ws + (2u << 20));         // 2 MB
  unsigned short* Vb = (unsigned short*)(ws + (4u << 20));         // 2 MB
  unsigned short* Vt = (unsigned short*)(ws + (6u << 20));         // 2 MB
  float*          AO = (float*)(ws + (8u << 20));                  // 4 MB
  unsigned long long* Mk = (unsigned long long*)(ws + (12u << 20)); // 1 MB

  build_mask<<<dim3((BB * NNN * NNN) / 256), 256, 0, stream>>>(adj, Mk);
  qkv_proj<<<dim3((BB * NNN) / 16), 256, 0, stream>>>(x, Wq, Wk, Wv, Qb, Kb, Vb);
  transpose_v<<<dim3(NNN / 64, BB * HH), 256, 0, stream>>>(Vb, Vt);
  attn<<<dim3(NNN / 64, HH, BB), 256, 0, stream>>>(Qb, Kb, Vt, Mk, AO);
  out_proj<<<dim3((BB * NNN) / 16), 256, 0, stream>>>(AO, Wo, bo, out);
}

// Round 2
// 188.385 us; speedup vs baseline: 1.4544x; 1.4544x over previous
//
#include <hip/hip_runtime.h>

#define BB   2
#define NNN  2048
#define DIN  256
#define HH   8
#define DHD  32
#define NW   (NNN/64)   // 32 mask words per row

typedef __attribute__((ext_vector_type(8))) short short8;
typedef __attribute__((ext_vector_type(4))) short short4v;
typedef __attribute__((ext_vector_type(4))) float f32x4;

__device__ __forceinline__ unsigned short f2bf(float f) {
  unsigned int u = __float_as_uint(f);
  u += 0x7fffu + ((u >> 16) & 1u);   // round-to-nearest-even
  return (unsigned short)(u >> 16);
}

#define QSCALE (0.17677669529663687f * 1.4426950408889634f)  // 1/sqrt(32) * log2(e)

// ---------------- K_cast: Wq,Wk,Wv fp32 -> bf16 ----------------
__global__ __launch_bounds__(256) void cast_w(const float* __restrict__ s0,
                                              const float* __restrict__ s1,
                                              const float* __restrict__ s2,
                                              unsigned short* __restrict__ dst) {
  const float* srcs[3] = {s0, s1, s2};
  const float* s = srcs[blockIdx.y];
  int i = blockIdx.x * 1024 + threadIdx.x * 4;
  float4 v = *(const float4*)(s + i);
  unsigned short t[4] = {f2bf(v.x), f2bf(v.y), f2bf(v.z), f2bf(v.w)};
  *(short4v*)(dst + (size_t)blockIdx.y * 65536 + i) = *(const short4v*)t;
}

// ---------------- K0: adjacency -> 64-bit masks ----------------
__global__ __launch_bounds__(256) void build_mask(const float* __restrict__ adj,
                                                  unsigned long long* __restrict__ Mk) {
  size_t i = (size_t)blockIdx.x * 256 + threadIdx.x;   // over B*N*N
  float v = adj[i];
  unsigned long long bm = __ballot(v != 0.0f);
  if ((threadIdx.x & 63) == 0) Mk[i >> 6] = bm;
}

// ---------------- K1: QKV projection via bf16 MFMA ----------------
// single-wave blocks; wave computes 16 rows x 64 out-cols; grid (256, 12)
__global__ __launch_bounds__(64) void qkv_gemm(
    const float* __restrict__ x, const unsigned short* __restrict__ Wb,
    unsigned short* __restrict__ Qb, unsigned short* __restrict__ Kb,
    unsigned short* __restrict__ Vb) {
  const int l = threadIdx.x, col = l & 15, quad = l >> 4;
  const int row0 = blockIdx.x * 16;
  const int y = blockIdx.y;            // 0..11
  const int mat = y >> 2;              // 0=Q 1=K 2=V
  const int ocb = (y & 3) * 64;
  const unsigned short* W = Wb + (size_t)mat * 65536;

  f32x4 acc[4];
  #pragma unroll
  for (int c = 0; c < 4; ++c) acc[c] = (f32x4){0.f, 0.f, 0.f, 0.f};

  #pragma unroll
  for (int kk = 0; kk < 8; ++kk) {
    const float* xp = x + (size_t)(row0 + col) * DIN + kk * 32 + quad * 8;
    float4 a0 = *(const float4*)xp;
    float4 a1 = *(const float4*)(xp + 4);
    short8 af;
    af[0] = (short)f2bf(a0.x); af[1] = (short)f2bf(a0.y);
    af[2] = (short)f2bf(a0.z); af[3] = (short)f2bf(a0.w);
    af[4] = (short)f2bf(a1.x); af[5] = (short)f2bf(a1.y);
    af[6] = (short)f2bf(a1.z); af[7] = (short)f2bf(a1.w);
    #pragma unroll
    for (int c = 0; c < 4; ++c) {
      short8 bw = *(const short8*)(W + (size_t)(ocb + c * 16 + col) * DIN + kk * 32 + quad * 8);
      acc[c] = __builtin_amdgcn_mfma_f32_16x16x32_bf16(af, bw, acc[c], 0, 0, 0);
    }
  }

  unsigned short* dst = (mat == 0) ? Qb : (mat == 1) ? Kb : Vb;
  const float scale = (mat == 0) ? QSCALE : 1.0f;
  #pragma unroll
  for (int c = 0; c < 4; ++c) {
    int oc = ocb + c * 16 + col, h = oc >> 5, dh = oc & 31;
    #pragma unroll
    for (int r = 0; r < 4; ++r) {
      int row = row0 + quad * 4 + r;
      int b = row >> 11, n = row & (NNN - 1);
      dst[((size_t)(b * HH + h) * NNN + n) * DHD + dh] = f2bf(acc[c][r] * scale);
    }
  }
}

// ---------------- K1b: V -> V^T  (Vt[bh][dh][n]) ----------------
__global__ __launch_bounds__(256) void transpose_v(const unsigned short* __restrict__ Vb,
                                                   unsigned short* __restrict__ Vt) {
  __shared__ __align__(16) unsigned short tile[64][48];
  const int t = threadIdx.x;
  const int nb = blockIdx.x * 64;
  const int bh = blockIdx.y;
  {
    int nr = t >> 2, c0 = (t & 3) * 8;
    short8 v = *(const short8*)(Vb + ((size_t)bh * NNN + nb + nr) * DHD + c0);
    *(short8*)&tile[nr][c0] = v;
  }
  __syncthreads();
  {
    int dh = t >> 3, n0 = (t & 7) * 8;
    unsigned short tmp[8];
    #pragma unroll
    for (int j = 0; j < 8; ++j) tmp[j] = tile[n0 + j][dh];
    *(short8*)(Vt + ((size_t)bh * DHD + dh) * NNN + nb + n0) = *(const short8*)tmp;
  }
}

// ---------------- K2: fused masked flash attention (transposed scores) ----------------
// single-wave blocks: wave handles 16 queries; S^T = K*Q^T so each lane owns one query
__global__ __launch_bounds__(64) void attn(
    const unsigned short* __restrict__ Qb, const unsigned short* __restrict__ Kb,
    const unsigned short* __restrict__ Vt, const unsigned long long* __restrict__ Mk,
    float* __restrict__ AO) {
  __shared__ __align__(16) unsigned short P2[2][16][68];  // [buf][query][64 keys + pad]
  const int l = threadIdx.x, col = l & 15, quad = l >> 4;
  const int qt = blockIdx.x, h = blockIdx.y, b = blockIdx.z;
  const int bh = b * HH + h;
  const int q = qt * 16 + col;   // this lane's query (replicated across 4 quads)

  // Q as B-operand: B[n=query=col][k=dh=quad*8+j]
  const short8 bq = *(const short8*)(Qb + ((size_t)bh * NNN + q) * DHD + quad * 8);

  f32x4 accT0 = {0.f, 0.f, 0.f, 0.f}, accT1 = {0.f, 0.f, 0.f, 0.f};  // O^T: d=quad*4+r(+16), n=query
  float mi = -1e30f, li = 0.f;
  const unsigned long long* mrow = Mk + (size_t)(b * NNN + q) * NW;

  for (int kt = 0; kt < NW; ++kt) {
    const int kb = kt * 64;
    const unsigned long long mq = mrow[kt] >> (quad * 4);  // pre-shift by quad

    short8 ak[4], av[2][2];
    #pragma unroll
    for (int c = 0; c < 4; ++c)
      ak[c] = *(const short8*)(Kb + ((size_t)bh * NNN + kb + c * 16 + col) * DHD + quad * 8);
    #pragma unroll
    for (int dt = 0; dt < 2; ++dt)
      #pragma unroll
      for (int ch = 0; ch < 2; ++ch)
        av[dt][ch] = *(const short8*)(Vt + ((size_t)bh * DHD + dt * 16 + col) * NNN + kb + ch * 32 + quad * 8);

    // S^T: A=K (m=key), B=Q (n=query). lane holds keys kb + c*16 + quad*4 + r for query col
    const f32x4 z = {0.f, 0.f, 0.f, 0.f};
    f32x4 st[4];
    #pragma unroll
    for (int c = 0; c < 4; ++c)
      st[c] = __builtin_amdgcn_mfma_f32_16x16x32_bf16(ak[c], bq, z, 0, 0, 0);

    float tv[16];
    #pragma unroll
    for (int c = 0; c < 4; ++c)
      #pragma unroll
      for (int r = 0; r < 4; ++r) {
        bool ok = (mq >> (c * 16 + r)) & 1ull;
        tv[c * 4 + r] = ok ? st[c][r] : -1e30f;
      }
    // in-lane max of 16, then cross-quad (same query) reduce
    float m8[8];
    #pragma unroll
    for (int i = 0; i < 8; ++i) m8[i] = fmaxf(tv[i], tv[i + 8]);
    float m4a = fmaxf(m8[0], m8[4]), m4b = fmaxf(m8[1], m8[5]);
    float m4c = fmaxf(m8[2], m8[6]), m4d = fmaxf(m8[3], m8[7]);
    float vm = fmaxf(fmaxf(m4a, m4b), fmaxf(m4c, m4d));
    vm = fmaxf(vm, __shfl_xor(vm, 16, 64));
    vm = fmaxf(vm, __shfl_xor(vm, 32, 64));

    float mnew = fmaxf(mi, vm);
    float alpha = exp2f(mi - mnew);
    float gate = (mnew > -1e29f) ? 1.0f : 0.0f;  // all-masked-so-far guard

    float p[16];
    #pragma unroll
    for (int i = 0; i < 16; ++i) p[i] = exp2f(tv[i] - mnew) * gate;  // masked: exp2(-1e30)->0

    float s8[8];
    #pragma unroll
    for (int i = 0; i < 8; ++i) s8[i] = p[i] + p[i + 8];
    float rs = ((s8[0] + s8[4]) + (s8[1] + s8[5])) + ((s8[2] + s8[6]) + (s8[3] + s8[7]));
    rs += __shfl_xor(rs, 16, 64);
    rs += __shfl_xor(rs, 32, 64);

    li = li * alpha + rs;
    mi = mnew;
    #pragma unroll
    for (int r = 0; r < 4; ++r) { accT0[r] *= alpha; accT1[r] *= alpha; }

    // P^T -> LDS row[query=col]: keys in order; lane writes its 16 bf16 (4x ds_write_b64)
    const int buf = kt & 1;
    #pragma unroll
    for (int c = 0; c < 4; ++c) {
      unsigned short pk[4] = {f2bf(p[c * 4]), f2bf(p[c * 4 + 1]), f2bf(p[c * 4 + 2]), f2bf(p[c * 4 + 3])};
      *(short4v*)&P2[buf][col][c * 16 + quad * 4] = *(const short4v*)pk;
    }
    __syncthreads();  // single wave: compiles to a cheap lgkm drain (+no-op barrier)

    // B-frags of P^T: B[n=query=col][k=quad*8+j] = contiguous 16B of the row
    union { short8 v8; short4v v4[2]; } u0, u1;
    u0.v4[0] = *(const short4v*)&P2[buf][col][quad * 8];
    u0.v4[1] = *(const short4v*)&P2[buf][col][quad * 8 + 4];
    u1.v4[0] = *(const short4v*)&P2[buf][col][32 + quad * 8];
    u1.v4[1] = *(const short4v*)&P2[buf][col][32 + quad * 8 + 4];

    // O^T += V^T * P^T
    accT0 = __builtin_amdgcn_mfma_f32_16x16x32_bf16(av[0][0], u0.v8, accT0, 0, 0, 0);
    accT0 = __builtin_amdgcn_mfma_f32_16x16x32_bf16(av[0][1], u1.v8, accT0, 0, 0, 0);
    accT1 = __builtin_amdgcn_mfma_f32_16x16x32_bf16(av[1][0], u0.v8, accT1, 0, 0, 0);
    accT1 = __builtin_amdgcn_mfma_f32_16x16x32_bf16(av[1][1], u1.v8, accT1, 0, 0, 0);
  }

  float inv = 1.0f / li;
  float* dst = AO + ((size_t)(b * NNN + q)) * (HH * DHD) + h * DHD;
  #pragma unroll
  for (int r = 0; r < 4; ++r) {
    dst[quad * 4 + r]      = accT0[r] * inv;
    dst[16 + quad * 4 + r] = accT1[r] * inv;
  }
}

// ---------------- K3: output projection + bias (fp32, occupancy-fixed) ----------------
// block=128 threads: 8 rows x 128 cols; grid (512, 2). AO row loads are wave-uniform.
__global__ __launch_bounds__(128) void out_proj(const float* __restrict__ AO,
                                                const float* __restrict__ Wo,
                                                const float* __restrict__ bo,
                                                float* __restrict__ out) {
  const int t = threadIdx.x;
  const int row0 = blockIdx.x * 8;
  const int col = blockIdx.y * 128 + t;

  float acc[8];
  #pragma unroll
  for (int r = 0; r < 8; ++r) acc[r] = 0.f;

  const float4* wp = (const float4*)(Wo + (size_t)col * DIN);
  #pragma unroll 4
  for (int k = 0; k < DIN / 4; ++k) {
    float4 w4 = wp[k];
    #pragma unroll
    for (int r = 0; r < 8; ++r) {
      float4 xr = *(const float4*)(AO + (size_t)(row0 + r) * DIN + k * 4);
      acc[r] += xr.x * w4.x + xr.y * w4.y + xr.z * w4.z + xr.w * w4.w;
    }
  }
  float bias = bo[col];
  #pragma unroll
  for (int r = 0; r < 8; ++r) out[(size_t)(row0 + r) * DIN + col] = acc[r] + bias;
}

extern "C" void kernel_launch(void* const* d_in, const int* in_sizes, int n_in,
                              void* d_out, int out_size, void* d_ws, size_t ws_size,
                              hipStream_t stream) {
  const float* x   = (const float*)d_in[0];
  const float* adj = (const float*)d_in[1];
  const float* Wq  = (const float*)d_in[2];
  const float* Wk  = (const float*)d_in[3];
  const float* Wv  = (const float*)d_in[4];
  const float* Wo  = (const float*)d_in[5];
  const float* bo  = (const float*)d_in[6];
  float* out = (float*)d_out;

  char* ws = (char*)d_ws;
  unsigned short* Qb = (unsigned short*)(ws);                        // 2 MB
  unsigned short* Kb = (unsigned short*)(ws + (2u << 20));           // 2 MB
  unsigned short* Vb = (unsigned short*)(ws + (4u << 20));           // 2 MB
  unsigned short* Vt = (unsigned short*)(ws + (6u << 20));           // 2 MB
  float*          AO = (float*)(ws + (8u << 20));                    // 4 MB fp32
  unsigned long long* Mk = (unsigned long long*)(ws + (12u << 20));  // 1 MB
  unsigned short* Wb = (unsigned short*)(ws + (13u << 20));          // 384 KB (Wq,Wk,Wv bf16)

  cast_w<<<dim3(64, 3), 256, 0, stream>>>(Wq, Wk, Wv, Wb);
  build_mask<<<dim3((BB * NNN * NNN) / 256), 256, 0, stream>>>(adj, Mk);
  qkv_gemm<<<dim3(BB * NNN / 16, 12), 64, 0, stream>>>(x, Wb, Qb, Kb, Vb);
  transpose_v<<<dim3(NNN / 64, BB * HH), 256, 0, stream>>>(Vb, Vt);
  attn<<<dim3(NNN / 16, HH, BB), 64, 0, stream>>>(Qb, Kb, Vt, Mk, AO);
  out_proj<<<dim3(BB * NNN / 8, 2), 128, 0, stream>>>(AO, Wo, bo, out);
}

// Round 3
// 177.286 us; speedup vs baseline: 1.5455x; 1.0626x over previous
//
#include <hip/hip_runtime.h>

#define BB   2
#define NNN  2048
#define DIN  256
#define HH   8
#define DHD  32
#define NW   (NNN/64)   // 32 mask words per row

typedef __attribute__((ext_vector_type(8))) short short8;
typedef __attribute__((ext_vector_type(4))) short short4v;
typedef __attribute__((ext_vector_type(4))) float f32x4;
typedef __attribute__((ext_vector_type(16))) float f32x16;

__device__ __forceinline__ unsigned short f2bf(float f) {
  unsigned int u = __float_as_uint(f);
  u += 0x7fffu + ((u >> 16) & 1u);   // round-to-nearest-even
  return (unsigned short)(u >> 16);
}

#define QSCALE (0.17677669529663687f * 1.4426950408889634f)  // 1/sqrt(32) * log2(e)

// ---------------- cast Wq,Wk,Wv fp32 -> bf16 ----------------
__global__ __launch_bounds__(256) void cast_w(const float* __restrict__ s0,
                                              const float* __restrict__ s1,
                                              const float* __restrict__ s2,
                                              unsigned short* __restrict__ dst) {
  const float* srcs[3] = {s0, s1, s2};
  const float* s = srcs[blockIdx.y];
  int i = blockIdx.x * 1024 + threadIdx.x * 4;
  float4 v = *(const float4*)(s + i);
  unsigned short t[4] = {f2bf(v.x), f2bf(v.y), f2bf(v.z), f2bf(v.w)};
  *(short4v*)(dst + (size_t)blockIdx.y * 65536 + i) = *(const short4v*)t;
}

// ---------------- Wo -> Wo^T (fp32), for coalesced out_proj ----------------
__global__ __launch_bounds__(256) void trans_wo(const float* __restrict__ Wo,
                                                float* __restrict__ Wot) {
  __shared__ float tl[32][33];
  const int c = threadIdx.x & 31, r8 = threadIdx.x >> 5;
  const int bx = blockIdx.x, by = blockIdx.y;
  #pragma unroll
  for (int i = 0; i < 4; ++i) {
    int r = r8 + i * 8;
    tl[r][c] = Wo[(size_t)(by * 32 + r) * DIN + bx * 32 + c];
  }
  __syncthreads();
  #pragma unroll
  for (int i = 0; i < 4; ++i) {
    int r = r8 + i * 8;
    Wot[(size_t)(bx * 32 + r) * DIN + by * 32 + c] = tl[c][r];
  }
}

// ---------------- adjacency -> 64-bit masks ----------------
__global__ __launch_bounds__(256) void build_mask(const float* __restrict__ adj,
                                                  unsigned long long* __restrict__ Mk) {
  size_t i = (size_t)blockIdx.x * 256 + threadIdx.x;   // over B*N*N
  float v = adj[i];
  unsigned long long bm = __ballot(v != 0.0f);
  if ((threadIdx.x & 63) == 0) Mk[i >> 6] = bm;
}

// ---------------- QKV projection via bf16 MFMA (V stored transposed) ----------------
__global__ __launch_bounds__(64) void qkv_gemm(
    const float* __restrict__ x, const unsigned short* __restrict__ Wb,
    unsigned short* __restrict__ Qb, unsigned short* __restrict__ Kb,
    unsigned short* __restrict__ Vt) {
  const int l = threadIdx.x, col = l & 15, quad = l >> 4;
  const int row0 = blockIdx.x * 16;
  const int y = blockIdx.y;            // 0..11
  const int mat = y >> 2;              // 0=Q 1=K 2=V
  const int ocb = (y & 3) * 64;
  const unsigned short* W = Wb + (size_t)mat * 65536;

  f32x4 acc[4];
  #pragma unroll
  for (int c = 0; c < 4; ++c) acc[c] = (f32x4){0.f, 0.f, 0.f, 0.f};

  #pragma unroll
  for (int kk = 0; kk < 8; ++kk) {
    const float* xp = x + (size_t)(row0 + col) * DIN + kk * 32 + quad * 8;
    float4 a0 = *(const float4*)xp;
    float4 a1 = *(const float4*)(xp + 4);
    short8 af;
    af[0] = (short)f2bf(a0.x); af[1] = (short)f2bf(a0.y);
    af[2] = (short)f2bf(a0.z); af[3] = (short)f2bf(a0.w);
    af[4] = (short)f2bf(a1.x); af[5] = (short)f2bf(a1.y);
    af[6] = (short)f2bf(a1.z); af[7] = (short)f2bf(a1.w);
    #pragma unroll
    for (int c = 0; c < 4; ++c) {
      short8 bw = *(const short8*)(W + (size_t)(ocb + c * 16 + col) * DIN + kk * 32 + quad * 8);
      acc[c] = __builtin_amdgcn_mfma_f32_16x16x32_bf16(af, bw, acc[c], 0, 0, 0);
    }
  }

  const float scale = (mat == 0) ? QSCALE : 1.0f;
  #pragma unroll
  for (int c = 0; c < 4; ++c) {
    int oc = ocb + c * 16 + col, h = oc >> 5, dh = oc & 31;
    #pragma unroll
    for (int r = 0; r < 4; ++r) {
      int row = row0 + quad * 4 + r;
      int b = row >> 11, n = row & (NNN - 1);
      unsigned short val = f2bf(acc[c][r] * scale);
      if (mat == 2)
        Vt[((size_t)(b * HH + h) * DHD + dh) * NNN + n] = val;      // V^T[bh][dh][n]
      else if (mat == 0)
        Qb[((size_t)(b * HH + h) * NNN + n) * DHD + dh] = val;
      else
        Kb[((size_t)(b * HH + h) * NNN + n) * DHD + dh] = val;
    }
  }
}

// ---------------- fused masked attention, no-max softmax, key-split ----------------
// 1 wave per block, 32 queries/wave (32x32x16 MFMA); writes unnormalized partials
__global__ __launch_bounds__(64) void attn(
    const unsigned short* __restrict__ Qb, const unsigned short* __restrict__ Kb,
    const unsigned short* __restrict__ Vt, const unsigned long long* __restrict__ Mk,
    float* __restrict__ Op, float* __restrict__ Lp, int nt) {
  __shared__ __align__(16) unsigned short P[32][40];   // [query][32 keys + pad]
  __shared__ float OL[32][33];                          // O transpose for coalesced store
  const int lane = threadIdx.x;
  const int qi = lane & 31, hi = lane >> 5;
  const int qt = blockIdx.x, bh = blockIdx.y, sp = blockIdx.z;
  const int b = bh >> 3;
  const int q = qt * 32 + qi;
  const int k0 = sp * nt * 32;

  // Q B-frag: B[n=query=qi][k = hi*8+j], dh chunks 0..15 / 16..31
  const unsigned short* qp = Qb + ((size_t)bh * NNN + q) * DHD + hi * 8;
  const short8 bq0 = *(const short8*)(qp);
  const short8 bq1 = *(const short8*)(qp + 16);

  f32x16 accO;
  #pragma unroll
  for (int i = 0; i < 16; ++i) accO[i] = 0.f;
  float lsum = 0.f;

  const unsigned long long* mrow = Mk + ((size_t)b * NNN + q) * NW + (k0 >> 6);
  const unsigned short* kbase = Kb + ((size_t)bh * NNN + k0 + qi) * DHD + hi * 8;  // qi = key here
  const unsigned short* vbase = Vt + ((size_t)bh * DHD + qi) * NNN + k0 + hi * 8;  // qi = dh here

  for (int w = 0; w < nt / 2; ++w) {
    unsigned long long mw = mrow[w];
    #pragma unroll
    for (int half = 0; half < 2; ++half) {
      const int kb = (w * 2 + half) * 32;
      const unsigned long long mq = mw >> (half * 32 + hi * 4);

      short8 ak0 = *(const short8*)(kbase + (size_t)kb * DHD);
      short8 ak1 = *(const short8*)(kbase + (size_t)kb * DHD + 16);

      f32x16 z;
      #pragma unroll
      for (int i = 0; i < 16; ++i) z[i] = 0.f;
      // S^T: A=K (m=key), B=Q (n=query); C: query=lane&31, key=(reg&3)+8*(reg>>2)+4*hi
      f32x16 st = __builtin_amdgcn_mfma_f32_32x32x16_bf16(ak0, bq0, z, 0, 0, 0);
      st = __builtin_amdgcn_mfma_f32_32x32x16_bf16(ak1, bq1, st, 0, 0, 0);

      float p[16];
      #pragma unroll
      for (int g = 0; g < 4; ++g)
        #pragma unroll
        for (int r = 0; r < 4; ++r) {
          bool ok = (mq >> (g * 8 + r)) & 1ull;
          float tv = ok ? st[g * 4 + r] : -1e30f;   // exp2(-1e30) -> 0
          float e = exp2f(tv);                       // no-max softmax: scores bounded
          p[g * 4 + r] = e;
          lsum += e;
        }

      // P^T rows: lane writes keys {g*8+hi*4 .. +3} of query qi
      #pragma unroll
      for (int g = 0; g < 4; ++g) {
        unsigned short pk[4] = {f2bf(p[g*4]), f2bf(p[g*4+1]), f2bf(p[g*4+2]), f2bf(p[g*4+3])};
        *(short4v*)&P[qi][g * 8 + hi * 4] = *(const short4v*)pk;
      }
      __syncthreads();  // single-wave: lgkm drain ordering cross-lane P visibility

      short8 pb0 = *(const short8*)&P[qi][hi * 8];
      short8 pb1 = *(const short8*)&P[qi][16 + hi * 8];
      short8 av0 = *(const short8*)(vbase + kb);
      short8 av1 = *(const short8*)(vbase + kb + 16);

      // O^T += V^T * P^T : C col=query, row=dh
      accO = __builtin_amdgcn_mfma_f32_32x32x16_bf16(av0, pb0, accO, 0, 0, 0);
      accO = __builtin_amdgcn_mfma_f32_32x32x16_bf16(av1, pb1, accO, 0, 0, 0);
      __syncthreads();  // P reuse next tile
    }
  }

  lsum += __shfl_xor(lsum, 32, 64);   // combine the two key-halves of this query

  // transpose O through LDS for coalesced partial store: Op[sp][bh][q][dh]
  #pragma unroll
  for (int g = 0; g < 4; ++g)
    #pragma unroll
    for (int r = 0; r < 4; ++r)
      OL[qi][g * 8 + hi * 4 + r] = accO[g * 4 + r];
  __syncthreads();
  float* obase = Op + (((size_t)(sp * 16 + bh)) * NNN + (size_t)qt * 32) * DHD;
  #pragma unroll
  for (int j = 0; j < 16; ++j) {
    int qq = j * 2 + hi;
    obase[(size_t)qq * DHD + qi] = OL[qq][qi];
  }
  if (hi == 0) Lp[((size_t)(sp * 16 + bh)) * NNN + q] = lsum;
}

// ---------------- combine split partials -> normalized AO ----------------
__global__ __launch_bounds__(256) void combine(const float* __restrict__ Op,
                                               const float* __restrict__ Lp,
                                               float* __restrict__ AO, int splits) {
  const int t = threadIdx.x;
  const int ql = t >> 5, dh = t & 31;
  const int q = blockIdx.x * 8 + ql;
  const int bh = blockIdx.y, b = bh >> 3, h = bh & 7;
  float o = 0.f, l = 0.f;
  for (int s = 0; s < splits; ++s) {
    o += Op[(((size_t)(s * 16 + bh)) * NNN + q) * DHD + dh];
    l += Lp[((size_t)(s * 16 + bh)) * NNN + q];
  }
  AO[((size_t)(b * NNN + q)) * DIN + h * DHD + dh] = o / l;
}

// ---------------- output projection + bias (fp32, coalesced W^T loads) ----------------
__global__ __launch_bounds__(256) void out_proj(const float* __restrict__ AO,
                                                const float* __restrict__ Wot,
                                                const float* __restrict__ bo,
                                                float* __restrict__ out) {
  const int t = threadIdx.x;
  const int row0 = blockIdx.x * 8;
  float acc[8];
  #pragma unroll
  for (int r = 0; r < 8; ++r) acc[r] = 0.f;

  const float* wp = Wot + t;
  #pragma unroll 2
  for (int k4 = 0; k4 < 64; ++k4) {
    float w0 = wp[(size_t)(k4 * 4 + 0) * DIN];
    float w1 = wp[(size_t)(k4 * 4 + 1) * DIN];
    float w2 = wp[(size_t)(k4 * 4 + 2) * DIN];
    float w3 = wp[(size_t)(k4 * 4 + 3) * DIN];
    #pragma unroll
    for (int r = 0; r < 8; ++r) {
      float4 a = *(const float4*)(AO + (size_t)(row0 + r) * DIN + k4 * 4);  // uniform -> SMEM
      acc[r] += a.x * w0 + a.y * w1 + a.z * w2 + a.w * w3;
    }
  }
  float bias = bo[t];
  #pragma unroll
  for (int r = 0; r < 8; ++r) out[(size_t)(row0 + r) * DIN + t] = acc[r] + bias;
}

extern "C" void kernel_launch(void* const* d_in, const int* in_sizes, int n_in,
                              void* d_out, int out_size, void* d_ws, size_t ws_size,
                              hipStream_t stream) {
  const float* x   = (const float*)d_in[0];
  const float* adj = (const float*)d_in[1];
  const float* Wq  = (const float*)d_in[2];
  const float* Wk  = (const float*)d_in[3];
  const float* Wv  = (const float*)d_in[4];
  const float* Wo  = (const float*)d_in[5];
  const float* bo  = (const float*)d_in[6];
  float* out = (float*)d_out;

  char* ws = (char*)d_ws;
  unsigned short* Qb = (unsigned short*)(ws);                         // 2 MB
  unsigned short* Kb = (unsigned short*)(ws + (2ull << 20));          // 2 MB
  unsigned short* Vt = (unsigned short*)(ws + (4ull << 20));          // 2 MB
  unsigned long long* Mk = (unsigned long long*)(ws + (6ull << 20));  // 1 MB
  unsigned short* Wb = (unsigned short*)(ws + (7ull << 20));          // 384 KB
  float* Wot = (float*)(ws + (7ull << 20) + (512ull << 10));          // 256 KB
  float* AO  = (float*)(ws + (8ull << 20));                           // 4 MB
  float* Lp  = (float*)(ws + (12ull << 20));                          // <=512 KB
  float* Op  = (float*)(ws + (12ull << 20) + (512ull << 10));         // 4 MB per split

  size_t base = (12ull << 20) + (512ull << 10);
  int splits = 1;
  if (ws_size >= base + 4ull * (4ull << 20)) splits = 4;
  else if (ws_size >= base + 2ull * (4ull << 20)) splits = 2;
  const int nt = (NNN / 32) / splits;

  cast_w<<<dim3(64, 3), 256, 0, stream>>>(Wq, Wk, Wv, Wb);
  trans_wo<<<dim3(8, 8), 256, 0, stream>>>(Wo, Wot);
  build_mask<<<dim3((BB * NNN * NNN) / 256), 256, 0, stream>>>(adj, Mk);
  qkv_gemm<<<dim3(BB * NNN / 16, 12), 64, 0, stream>>>(x, Wb, Qb, Kb, Vt);
  attn<<<dim3(NNN / 32, BB * HH, splits), 64, 0, stream>>>(Qb, Kb, Vt, Mk, Op, Lp, nt);
  combine<<<dim3(NNN / 8, BB * HH), 256, 0, stream>>>(Op, Lp, AO, splits);
  out_proj<<<dim3(BB * NNN / 8), 256, 0, stream>>>(AO, Wot, bo, out);
}